// Round 3
// baseline (489.392 us; speedup 1.0000x reference)
//
#include <hip/hip_runtime.h>
#include <hip/hip_bf16.h>

#define DEV __device__ __forceinline__

typedef __attribute__((ext_vector_type(8))) short bf16x8;
typedef __attribute__((ext_vector_type(8))) unsigned short u16x8;
typedef __attribute__((ext_vector_type(4))) float f32x4;

DEV unsigned short f2bf(float f) {
  return __builtin_bit_cast(unsigned short, __float2bfloat16(f));
}
DEV float bf2f(unsigned short h) { return __uint_as_float(((unsigned int)h) << 16); }

// LDS swizzles. 128B rows (BK=64 tiles): XOR 16B-slot with (row&7).
DEV int swz(int row, int byteoff) { return row * 128 + (byteoff ^ ((row & 7) << 4)); }
// 64B rows (BK=32 tiles): 4 slots of 16B, XOR with (row>>1)&3 -> balanced banks.
DEV int swz32(int row, int slot) { return row * 64 + ((slot ^ ((row >> 1) & 3)) << 4); }

// ---------------------------------------------------------------- cvt fp32->bf16 (8 segments, one launch)
struct CvtJobs { const float* s[8]; unsigned short* d[8]; float* df[8]; int n[8]; };
__global__ void cvtw_kernel(CvtJobs J) {
  const int seg = blockIdx.y;
  const float* __restrict__ src = J.s[seg];
  unsigned short* __restrict__ dst = J.d[seg];
  float* __restrict__ dstf = J.df[seg];
  const int n = J.n[seg];
  long i = ((long)blockIdx.x * blockDim.x + threadIdx.x) * 8;
  long stride = (long)gridDim.x * blockDim.x * 8;
  for (; i < n; i += stride) {
    f32x4 a = *(const f32x4*)(src + i);
    f32x4 b = *(const f32x4*)(src + i + 4);
    u16x8 o;
    o[0] = f2bf(a[0]); o[1] = f2bf(a[1]); o[2] = f2bf(a[2]); o[3] = f2bf(a[3]);
    o[4] = f2bf(b[0]); o[5] = f2bf(b[1]); o[6] = f2bf(b[2]); o[7] = f2bf(b[3]);
    *(u16x8*)(dst + i) = o;
    if (dstf) { *(f32x4*)(dstf + i) = a; *(f32x4*)(dstf + i + 4) = b; }
  }
}

// ---------------------------------------------------------------- GEMM (generic tile)
// Y[m,n] = act( sum_k X[m,k]*W[n,k] + bias[n] ). BM x 64 tile, BK=64, 4 waves.
// Reg-staged double-buffered pipeline, 1 barrier per K-step.
template <int BM, int ACT, int WF32, int WBF>
__global__ __launch_bounds__(256) void gemm_kernel(
    const unsigned short* __restrict__ X, const unsigned short* __restrict__ Wt,
    const float* __restrict__ bias, float* Yf, unsigned short* __restrict__ Ybf,
    int M, int N, int K, long xbs, long wbs, long bbs, long ybs) {
  constexpr int CA = (BM * 64) / (256 * 8);
  constexpr int ABY = BM * 64 * 2;
  constexpr int BBY = 64 * 64 * 2;
  constexpr int MI = BM / 32;
  __shared__ __align__(16) char Asb[2 * ABY];
  __shared__ __align__(16) char Bsb[2 * BBY];
  const int t = threadIdx.x;
  const int bn = blockIdx.x, bm = blockIdx.y, bz = blockIdx.z;
  const unsigned short* Xp = X + (long)bz * xbs;
  const unsigned short* Wp = Wt + (long)bz * wbs;

  const int lane = t & 63, wv = t >> 6;
  const int wr = wv >> 1, wc = wv & 1;
  f32x4 acc[MI][2] = {};

  int rowA[CA], slotA[CA], rowB[2], slotB[2];
#pragma unroll
  for (int c = 0; c < CA; ++c) { int id = c * 256 + t; rowA[c] = id >> 3; slotA[c] = id & 7; }
#pragma unroll
  for (int c = 0; c < 2; ++c) { int id = c * 256 + t; rowB[c] = id >> 3; slotB[c] = id & 7; }

  u16x8 ra[CA], rb[2];
  auto load = [&](int kt) {
#pragma unroll
    for (int c = 0; c < CA; ++c)
      ra[c] = *(const u16x8*)(Xp + (long)(bm * BM + rowA[c]) * K + kt + slotA[c] * 8);
#pragma unroll
    for (int c = 0; c < 2; ++c)
      rb[c] = *(const u16x8*)(Wp + (long)(bn * 64 + rowB[c]) * K + kt + slotB[c] * 8);
  };
  auto store = [&](int cur) {
#pragma unroll
    for (int c = 0; c < CA; ++c)
      *(u16x8*)(Asb + cur * ABY + swz(rowA[c], slotA[c] * 16)) = ra[c];
#pragma unroll
    for (int c = 0; c < 2; ++c)
      *(u16x8*)(Bsb + cur * BBY + swz(rowB[c], slotB[c] * 16)) = rb[c];
  };

  const int NT = K >> 6;
  load(0);
  store(0);
  load(64);
  __syncthreads();
  for (int ki = 0; ki < NT; ++ki) {
    const int cur = ki & 1;
    if (ki + 1 < NT) store(cur ^ 1);
    if (ki + 2 < NT) load((ki + 2) << 6);
#pragma unroll
    for (int kk = 0; kk < 2; ++kk) {
      const int kb = kk * 64 + ((lane >> 4) << 4);
      bf16x8 af[MI], bfv[2];
#pragma unroll
      for (int mi = 0; mi < MI; ++mi)
        af[mi] = *(const bf16x8*)(Asb + cur * ABY + swz(wr * (MI * 16) + mi * 16 + (lane & 15), kb));
#pragma unroll
      for (int ni = 0; ni < 2; ++ni)
        bfv[ni] = *(const bf16x8*)(Bsb + cur * BBY + swz(wc * 32 + ni * 16 + (lane & 15), kb));
#pragma unroll
      for (int mi = 0; mi < MI; ++mi)
#pragma unroll
        for (int ni = 0; ni < 2; ++ni)
          acc[mi][ni] = __builtin_amdgcn_mfma_f32_16x16x32_bf16(af[mi], bfv[ni], acc[mi][ni], 0, 0, 0);
    }
    __syncthreads();
  }
#pragma unroll
  for (int ni = 0; ni < 2; ++ni) {
    const int n = bn * 64 + wc * 32 + ni * 16 + (lane & 15);
    const float bv = bias[(long)bz * bbs + n];
#pragma unroll
    for (int mi = 0; mi < MI; ++mi) {
#pragma unroll
      for (int rr = 0; rr < 4; ++rr) {
        const int gm = bm * BM + wr * (MI * 16) + mi * 16 + ((lane >> 4) << 2) + rr;
        float v = acc[mi][ni][rr] + bv;
        if (ACT == 1) v = fmaxf(v, 0.f);
        const long o = (long)bz * ybs + (long)gm * N + n;
        if (WF32) Yf[o] = v;
        if (WBF) Ybf[o] = f2bf(v);
      }
    }
  }
}

// ---------------------------------------------------------------- GEMM + residual + LN (full-row blocks)
// Y = X*W^T + bias; u = Y + res; o1 = LN(u; g1,b1); [o2 = LN(o1; g2,b2)]
// Writes h (f32, in-place res ok) and hbf (bf16). M=1024, N=512, BM=32, BK=32.
template <int DOUBLE>
__global__ __launch_bounds__(256) void gemm_ln_kernel(
    const unsigned short* __restrict__ X, const unsigned short* __restrict__ Wt,
    const float* __restrict__ bias, float* __restrict__ h,
    unsigned short* __restrict__ hbf,
    const float* __restrict__ g1, const float* __restrict__ b1,
    const float* __restrict__ g2, const float* __restrict__ b2, int K) {
  constexpr int ABY = 32 * 32 * 2;    // 2KB
  constexpr int BBY = 512 * 32 * 2;   // 32KB
  __shared__ __align__(16) char Asb[2 * ABY];
  __shared__ __align__(16) char Bsb[2 * BBY];
  __shared__ float RedS[4][32], RedQ[4][32], RedS2[4][32], RedQ2[4][32];
  const int t = threadIdx.x;
  const int bm = blockIdx.x;
  const int lane = t & 63, wv = t >> 6;
  f32x4 acc[2][8] = {};

  const int arow = t >> 2, aslot = t & 3;  // threads 0..127 stage A
  u16x8 ra, rbv[8];
  auto load = [&](int kt) {
    if (t < 128) ra = *(const u16x8*)(X + (long)(bm * 32 + arow) * K + kt + aslot * 8);
#pragma unroll
    for (int c = 0; c < 8; ++c) {
      const int id = c * 256 + t, row = id >> 2, slot = id & 3;
      rbv[c] = *(const u16x8*)(Wt + (long)row * K + kt + slot * 8);
    }
  };
  auto store = [&](int cur) {
    if (t < 128) *(u16x8*)(Asb + cur * ABY + swz32(arow, aslot)) = ra;
#pragma unroll
    for (int c = 0; c < 8; ++c) {
      const int id = c * 256 + t, row = id >> 2, slot = id & 3;
      *(u16x8*)(Bsb + cur * BBY + swz32(row, slot)) = rbv[c];
    }
  };

  const int NT = K >> 5;
  load(0);
  store(0);
  load(32);
  __syncthreads();
  for (int ki = 0; ki < NT; ++ki) {
    const int cur = ki & 1;
    if (ki + 1 < NT) store(cur ^ 1);
    if (ki + 2 < NT) load((ki + 2) << 5);
    const int ks = lane >> 4;  // 16B k-slot
    bf16x8 af[2];
#pragma unroll
    for (int mi = 0; mi < 2; ++mi)
      af[mi] = *(const bf16x8*)(Asb + cur * ABY + swz32(mi * 16 + (lane & 15), ks));
#pragma unroll
    for (int ni = 0; ni < 8; ++ni) {
      bf16x8 bfv = *(const bf16x8*)(Bsb + cur * BBY + swz32(wv * 128 + ni * 16 + (lane & 15), ks));
#pragma unroll
      for (int mi = 0; mi < 2; ++mi)
        acc[mi][ni] = __builtin_amdgcn_mfma_f32_16x16x32_bf16(af[mi], bfv, acc[mi][ni], 0, 0, 0);
    }
    __syncthreads();
  }

  // ---- epilogue: u = acc + bias + res; LN over 512 cols per row.
  // u overwrites acc. col(ni) = wv*128 + ni*16 + (lane&15); row(mi,rr) = bm*32 + mi*16 + (lane>>4)*4 + rr.
  float ls[2][4], lq[2][4];
#pragma unroll
  for (int mi = 0; mi < 2; ++mi)
#pragma unroll
    for (int rr = 0; rr < 4; ++rr) {
      const int gm = bm * 32 + mi * 16 + ((lane >> 4) << 2) + rr;
      float s = 0.f, q = 0.f;
#pragma unroll
      for (int ni = 0; ni < 8; ++ni) {
        const int col = wv * 128 + ni * 16 + (lane & 15);
        float v = acc[mi][ni][rr] + bias[col] + h[(long)gm * 512 + col];
        acc[mi][ni][rr] = v;
        s += v; q += v * v;
      }
      ls[mi][rr] = s; lq[mi][rr] = q;
    }
#pragma unroll
  for (int msk = 1; msk < 16; msk <<= 1)
#pragma unroll
    for (int mi = 0; mi < 2; ++mi)
#pragma unroll
      for (int rr = 0; rr < 4; ++rr) {
        ls[mi][rr] += __shfl_xor(ls[mi][rr], msk, 64);
        lq[mi][rr] += __shfl_xor(lq[mi][rr], msk, 64);
      }
  if ((lane & 15) == 0) {
#pragma unroll
    for (int mi = 0; mi < 2; ++mi)
#pragma unroll
      for (int rr = 0; rr < 4; ++rr) {
        const int r = mi * 16 + ((lane >> 4) << 2) + rr;
        RedS[wv][r] = ls[mi][rr];
        RedQ[wv][r] = lq[mi][rr];
      }
  }
  __syncthreads();
#pragma unroll
  for (int mi = 0; mi < 2; ++mi)
#pragma unroll
    for (int rr = 0; rr < 4; ++rr) {
      const int r = mi * 16 + ((lane >> 4) << 2) + rr;
      const float S = RedS[0][r] + RedS[1][r] + RedS[2][r] + RedS[3][r];
      const float Q = RedQ[0][r] + RedQ[1][r] + RedQ[2][r] + RedQ[3][r];
      const float mean = S * (1.f / 512.f);
      const float var = Q * (1.f / 512.f) - mean * mean;
      const float inv = rsqrtf(var + 1e-5f);
      float s2 = 0.f, q2 = 0.f;
#pragma unroll
      for (int ni = 0; ni < 8; ++ni) {
        const int col = wv * 128 + ni * 16 + (lane & 15);
        float o1 = (acc[mi][ni][rr] - mean) * inv * g1[col] + b1[col];
        acc[mi][ni][rr] = o1;
        s2 += o1; q2 += o1 * o1;
      }
      ls[mi][rr] = s2; lq[mi][rr] = q2;
    }
  if (DOUBLE) {
#pragma unroll
    for (int msk = 1; msk < 16; msk <<= 1)
#pragma unroll
      for (int mi = 0; mi < 2; ++mi)
#pragma unroll
        for (int rr = 0; rr < 4; ++rr) {
          ls[mi][rr] += __shfl_xor(ls[mi][rr], msk, 64);
          lq[mi][rr] += __shfl_xor(lq[mi][rr], msk, 64);
        }
    if ((lane & 15) == 0) {
#pragma unroll
      for (int mi = 0; mi < 2; ++mi)
#pragma unroll
        for (int rr = 0; rr < 4; ++rr) {
          const int r = mi * 16 + ((lane >> 4) << 2) + rr;
          RedS2[wv][r] = ls[mi][rr];
          RedQ2[wv][r] = lq[mi][rr];
        }
    }
    __syncthreads();
#pragma unroll
    for (int mi = 0; mi < 2; ++mi)
#pragma unroll
      for (int rr = 0; rr < 4; ++rr) {
        const int r = mi * 16 + ((lane >> 4) << 2) + rr;
        const float S = RedS2[0][r] + RedS2[1][r] + RedS2[2][r] + RedS2[3][r];
        const float Q = RedQ2[0][r] + RedQ2[1][r] + RedQ2[2][r] + RedQ2[3][r];
        const float mean = S * (1.f / 512.f);
        const float var = Q * (1.f / 512.f) - mean * mean;
        const float inv = rsqrtf(var + 1e-5f);
#pragma unroll
        for (int ni = 0; ni < 8; ++ni) {
          const int col = wv * 128 + ni * 16 + (lane & 15);
          acc[mi][ni][rr] = (acc[mi][ni][rr] - mean) * inv * g2[col] + b2[col];
        }
      }
  }
  // write h (f32) + hbf (bf16)
#pragma unroll
  for (int mi = 0; mi < 2; ++mi)
#pragma unroll
    for (int rr = 0; rr < 4; ++rr) {
      const int gm = bm * 32 + mi * 16 + ((lane >> 4) << 2) + rr;
#pragma unroll
      for (int ni = 0; ni < 8; ++ni) {
        const int col = wv * 128 + ni * 16 + (lane & 15);
        const float v = acc[mi][ni][rr];
        h[(long)gm * 512 + col] = v;
        hbf[(long)gm * 512 + col] = f2bf(v);
      }
    }
}

// ---------------------------------------------------------------- attention
__global__ __launch_bounds__(256) void attn_kernel(const unsigned short* __restrict__ qkv,
                                                   unsigned short* __restrict__ o) {
  __shared__ float P[512];  // [h][l][m]
  const int s = blockIdx.x;
  const int t = threadIdx.x;
#pragma unroll
  for (int rep = 0; rep < 2; ++rep) {
    const int idx = t + rep * 256;
    const int h = idx >> 6, l = (idx >> 3) & 7, m = idx & 7;
    const unsigned short* qp = qkv + (long)(l * 128 + s) * 1536 + h * 64;
    const unsigned short* kp = qkv + (long)(m * 128 + s) * 1536 + 512 + h * 64;
    float acc = 0.f;
#pragma unroll
    for (int c = 0; c < 64; c += 8) {
      u16x8 q8 = *(const u16x8*)(qp + c);
      u16x8 k8 = *(const u16x8*)(kp + c);
#pragma unroll
      for (int j = 0; j < 8; ++j) acc += bf2f(q8[j]) * bf2f(k8[j]);
    }
    P[idx] = acc * 0.125f;
  }
  __syncthreads();
  if (t < 64) {
    const int base = t * 8;
    float mx = -1e30f;
#pragma unroll
    for (int m = 0; m < 8; ++m) mx = fmaxf(mx, P[base + m]);
    float e[8], sum = 0.f;
#pragma unroll
    for (int m = 0; m < 8; ++m) { e[m] = expf(P[base + m] - mx); sum += e[m]; }
    const float inv = 1.f / sum;
#pragma unroll
    for (int m = 0; m < 8; ++m) P[base + m] = e[m] * inv;
  }
  __syncthreads();
#pragma unroll
  for (int rep = 0; rep < 16; ++rep) {
    const int idx = t + rep * 256;  // l*512 + h*64 + d
    const int d = idx & 63, h = (idx >> 6) & 7, l = idx >> 9;
    float acc = 0.f;
#pragma unroll
    for (int m = 0; m < 8; ++m)
      acc += P[h * 64 + l * 8 + m] * bf2f(qkv[(long)(m * 128 + s) * 1536 + 1024 + h * 64 + d]);
    o[(long)(l * 128 + s) * 512 + h * 64 + d] = f2bf(acc);
  }
}

// ---------------------------------------------------------------- phase C
// p[b,i,j,k] = sum_d sub[b,j,d]*obj[b,k,d]*(vsub[b,i,d]*vobj[b,i,d])
__global__ __launch_bounds__(256) void phasec_kernel(const float* __restrict__ subp,
                                                     const unsigned short* __restrict__ objbf,
                                                     const float* __restrict__ vsub,
                                                     const float* __restrict__ vobj,
                                                     float* __restrict__ out) {
  constexpr int ABY = 128 * 64 * 2;  // 16 KiB per buffer per operand
  __shared__ __align__(16) char SMEM[67584];  // Asb(32K)|Bsb(32K)|Wl(2K); reused as C(128x132 f32)
  char* Asb = SMEM;
  char* Bsb = SMEM + 2 * ABY;
  float* Wl = (float*)(SMEM + 4 * ABY);
  const int t = threadIdx.x;
  const int i = blockIdx.x, b = blockIdx.y;
  const long base_bi = ((long)b * 128 + i) * 512;
  for (int d = t; d < 512; d += 256) Wl[d] = vsub[base_bi + d] * vobj[base_bi + d];

  const int lane = t & 63, wv = t >> 6;
  const int wr = wv >> 1, wc = wv & 1;
  f32x4 acc[4][4] = {};

  int row[4], slot[4];
#pragma unroll
  for (int c = 0; c < 4; ++c) { int id = c * 256 + t; row[c] = id >> 3; slot[c] = id & 7; }

  f32x4 fa[4][2];
  u16x8 rb[4];
  auto load = [&](int kt) {
#pragma unroll
    for (int c = 0; c < 4; ++c) {
      const long g = ((long)b * 128 + row[c]) * 512 + kt + slot[c] * 8;
      fa[c][0] = *(const f32x4*)(subp + g);
      fa[c][1] = *(const f32x4*)(subp + g + 4);
      rb[c] = *(const u16x8*)(objbf + g);
    }
  };
  auto store = [&](int cur, int ktd) {
#pragma unroll
    for (int c = 0; c < 4; ++c) {
      const float* wp = Wl + ktd + slot[c] * 8;
      f32x4 w0 = *(const f32x4*)wp;
      f32x4 w1 = *(const f32x4*)(wp + 4);
      u16x8 oa;
      oa[0] = f2bf(fa[c][0][0] * w0[0]); oa[1] = f2bf(fa[c][0][1] * w0[1]);
      oa[2] = f2bf(fa[c][0][2] * w0[2]); oa[3] = f2bf(fa[c][0][3] * w0[3]);
      oa[4] = f2bf(fa[c][1][0] * w1[0]); oa[5] = f2bf(fa[c][1][1] * w1[1]);
      oa[6] = f2bf(fa[c][1][2] * w1[2]); oa[7] = f2bf(fa[c][1][3] * w1[3]);
      *(u16x8*)(Asb + cur * ABY + swz(row[c], slot[c] * 16)) = oa;
      *(u16x8*)(Bsb + cur * ABY + swz(row[c], slot[c] * 16)) = rb[c];
    }
  };

  __syncthreads();  // Wl visible
  load(0);
  store(0, 0);
  load(64);
  __syncthreads();
  for (int ki = 0; ki < 8; ++ki) {
    const int cur = ki & 1;
    if (ki + 1 < 8) store(cur ^ 1, (ki + 1) * 64);
    if (ki + 2 < 8) load((ki + 2) * 64);
#pragma unroll
    for (int kk = 0; kk < 2; ++kk) {
      const int kb = kk * 64 + ((lane >> 4) << 4);
      bf16x8 af[4], bfv[4];
#pragma unroll
      for (int mi = 0; mi < 4; ++mi)
        af[mi] = *(const bf16x8*)(Asb + cur * ABY + swz(wr * 64 + mi * 16 + (lane & 15), kb));
#pragma unroll
      for (int ni = 0; ni < 4; ++ni)
        bfv[ni] = *(const bf16x8*)(Bsb + cur * ABY + swz(wc * 64 + ni * 16 + (lane & 15), kb));
#pragma unroll
      for (int mi = 0; mi < 4; ++mi)
#pragma unroll
        for (int ni = 0; ni < 4; ++ni)
          acc[mi][ni] = __builtin_amdgcn_mfma_f32_16x16x32_bf16(af[mi], bfv[ni], acc[mi][ni], 0, 0, 0);
    }
    __syncthreads();
  }
  // repack C through LDS for fully-coalesced float4 stores (stride 132 floats: 16B-aligned, bank-spread)
  float* C = (float*)SMEM;
#pragma unroll
  for (int mi = 0; mi < 4; ++mi)
#pragma unroll
    for (int rr = 0; rr < 4; ++rr) {
      const int j = wr * 64 + mi * 16 + ((lane >> 4) << 2) + rr;
      float* crow = C + j * 132 + wc * 64 + (lane & 15);
#pragma unroll
      for (int ni = 0; ni < 4; ++ni) crow[ni * 16] = acc[mi][ni][rr];
    }
  __syncthreads();
  float* ob = out + ((long)b * 128 + i) * 128 * 128;
  const int cc = (t & 31) * 4, jb = (t >> 5) * 16;
#pragma unroll
  for (int q = 0; q < 16; ++q) {
    const int j = jb + q;
    f32x4 v = *(const f32x4*)(C + j * 132 + cc);
    *(f32x4*)(ob + (long)j * 128 + cc) = v;
  }
}

// ---------------------------------------------------------------- launch
extern "C" void kernel_launch(void* const* d_in, const int* in_sizes, int n_in, void* d_out,
                              int out_size, void* d_ws, size_t ws_size, hipStream_t stream) {
  const float* x          = (const float*)d_in[0];
  const float* attn_in_w  = (const float*)d_in[1];
  const float* attn_in_b  = (const float*)d_in[2];
  const float* attn_out_w = (const float*)d_in[3];
  const float* attn_out_b = (const float*)d_in[4];
  const float* ln1_w = (const float*)d_in[5];
  const float* ln1_b = (const float*)d_in[6];
  const float* ln2_w = (const float*)d_in[7];
  const float* ln2_b = (const float*)d_in[8];
  const float* ff1_w = (const float*)d_in[9];
  const float* ff1_b = (const float*)d_in[10];
  const float* ff2_w = (const float*)d_in[11];
  const float* ff2_b = (const float*)d_in[12];
  const float* fln_w = (const float*)d_in[13];
  const float* fln_b = (const float*)d_in[14];
  const float* mlp_w0 = (const float*)d_in[15];
  const float* mlp_b0 = (const float*)d_in[16];
  const float* mlp_w1 = (const float*)d_in[17];
  const float* mlp_b1 = (const float*)d_in[18];
  const float* mlp_w2 = (const float*)d_in[19];
  const float* mlp_b2 = (const float*)d_in[20];
  float* out = (float*)d_out;
  (void)in_sizes; (void)n_in; (void)out_size; (void)ws_size;

  char* ws = (char*)d_ws;
  size_t off = 0;
  auto alloc = [&](size_t bytes) -> void* {
    void* p = (void*)(ws + off);
    off += (bytes + 255) & ~(size_t)255;
    return p;
  };
  unsigned short* wq  = (unsigned short*)alloc((size_t)3 * 1536 * 512 * 2);
  unsigned short* wo  = (unsigned short*)alloc((size_t)3 * 512 * 512 * 2);
  unsigned short* wf1 = (unsigned short*)alloc((size_t)3 * 2048 * 512 * 2);
  unsigned short* wf2 = (unsigned short*)alloc((size_t)3 * 512 * 2048 * 2);
  unsigned short* wm0 = (unsigned short*)alloc((size_t)4 * 512 * 512 * 2);
  unsigned short* wm1 = (unsigned short*)alloc((size_t)4 * 512 * 512 * 2);
  unsigned short* wm2 = (unsigned short*)alloc((size_t)4 * 512 * 512 * 2);
  float* h            = (float*)alloc((size_t)1024 * 512 * 4);
  unsigned short* hbf = (unsigned short*)alloc((size_t)1024 * 512 * 2);
  unsigned short* t1  = (unsigned short*)alloc((size_t)1024 * 2048 * 2);
  unsigned short* ao  = (unsigned short*)alloc((size_t)1024 * 512 * 2);
  unsigned short* z1  = (unsigned short*)alloc((size_t)4 * 1024 * 512 * 2);
  unsigned short* z2  = (unsigned short*)alloc((size_t)4 * 1024 * 512 * 2);
  float* hf4          = (float*)alloc((size_t)4 * 1024 * 512 * 4);
  unsigned short* hb4 = (unsigned short*)alloc((size_t)4 * 1024 * 512 * 2);

  CvtJobs J;
  for (int k = 0; k < 8; ++k) J.df[k] = nullptr;
  J.s[0] = attn_in_w;  J.d[0] = wq;  J.n[0] = 3 * 1536 * 512;
  J.s[1] = attn_out_w; J.d[1] = wo;  J.n[1] = 3 * 512 * 512;
  J.s[2] = ff1_w;      J.d[2] = wf1; J.n[2] = 3 * 2048 * 512;
  J.s[3] = ff2_w;      J.d[3] = wf2; J.n[3] = 3 * 512 * 2048;
  J.s[4] = mlp_w0;     J.d[4] = wm0; J.n[4] = 4 * 512 * 512;
  J.s[5] = mlp_w1;     J.d[5] = wm1; J.n[5] = 4 * 512 * 512;
  J.s[6] = mlp_w2;     J.d[6] = wm2; J.n[6] = 4 * 512 * 512;
  J.s[7] = x;          J.d[7] = hbf; J.n[7] = 1024 * 512; J.df[7] = h;
  cvtw_kernel<<<dim3(512, 8), 256, 0, stream>>>(J);

  for (int i = 0; i < 3; ++i) {
    gemm_kernel<64, 0, 0, 1><<<dim3(24, 16, 1), 256, 0, stream>>>(
        hbf, wq + (long)i * 1536 * 512, attn_in_b + i * 1536, nullptr, t1, 1024, 1536, 512, 0, 0, 0, 0);
    attn_kernel<<<128, 256, 0, stream>>>(t1, ao);
    gemm_ln_kernel<0><<<32, 256, 0, stream>>>(
        ao, wo + (long)i * 512 * 512, attn_out_b + i * 512, h, hbf,
        ln1_w + i * 512, ln1_b + i * 512, nullptr, nullptr, 512);
    gemm_kernel<64, 1, 0, 1><<<dim3(32, 16, 1), 256, 0, stream>>>(
        hbf, wf1 + (long)i * 2048 * 512, ff1_b + i * 2048, nullptr, t1, 1024, 2048, 512, 0, 0, 0, 0);
    if (i < 2)
      gemm_ln_kernel<0><<<32, 256, 0, stream>>>(
          t1, wf2 + (long)i * 512 * 2048, ff2_b + i * 512, h, hbf,
          ln2_w + i * 512, ln2_b + i * 512, nullptr, nullptr, 2048);
    else
      gemm_ln_kernel<1><<<32, 256, 0, stream>>>(
          t1, wf2 + (long)i * 512 * 2048, ff2_b + i * 512, h, hbf,
          ln2_w + i * 512, ln2_b + i * 512, fln_w, fln_b, 2048);
  }

  // 4 head-MLPs batched over blockIdx.z
  gemm_kernel<32, 1, 0, 1><<<dim3(8, 32, 4), 256, 0, stream>>>(
      hbf, wm0, mlp_b0, nullptr, z1, 1024, 512, 512, 0, 512 * 512, 512, 1024 * 512);
  gemm_kernel<32, 1, 0, 1><<<dim3(8, 32, 4), 256, 0, stream>>>(
      z1, wm1, mlp_b1, nullptr, z2, 1024, 512, 512, 1024 * 512, 512 * 512, 512, 1024 * 512);
  gemm_kernel<32, 0, 1, 1><<<dim3(8, 32, 4), 256, 0, stream>>>(
      z2, wm2, mlp_b2, hf4, hb4, 1024, 512, 512, 1024 * 512, 512 * 512, 512, 1024 * 512);

  // heads: 0=sub, 1=obj, 2=verb_sub, 3=verb_obj
  phasec_kernel<<<dim3(128, 8), 256, 0, stream>>>(
      hf4, hb4 + 1 * 1024 * 512, hf4 + 2L * 1024 * 512, hf4 + 3L * 1024 * 512, out);
}